// Round 2
// baseline (2824.822 us; speedup 1.0000x reference)
//
#include <hip/hip_runtime.h>
#include <cstdint>
#include <cstddef>

// Problem constants
#define BB 4
#define SS 4096
#define HH 1024
#define PP 10
#define LL 4106          // P + S
#define LPAD 4128        // 129 * 32 (zero-padded KV length, Path A)
#define NTILES 129       // KV tiles of 32
#define LOG2E 1.44269504088896f

typedef __attribute__((ext_vector_type(8))) short short8v;   // 8 x bf16 MFMA frag (4 VGPRs)
typedef __attribute__((ext_vector_type(4))) float float4v;
typedef __attribute__((ext_vector_type(4))) unsigned int uint4v;

union frag_cast { uint4v u; short8v s; };

__device__ __forceinline__ unsigned bf16rn1(float x) {
  unsigned u = __float_as_uint(x);
  return (u + 0x7FFFu + ((u >> 16) & 1u)) >> 16;
}
__device__ __forceinline__ unsigned packrn(float a, float b) {
  return bf16rn1(a) | (bf16rn1(b) << 16);
}
__device__ __forceinline__ float trunchi(float a) {
  return __uint_as_float(__float_as_uint(a) & 0xFFFF0000u);
}
__device__ __forceinline__ unsigned packtrunc(float a, float b) {
  return (__float_as_uint(a) >> 16) | (__float_as_uint(b) & 0xFFFF0000u);
}

__device__ __forceinline__ void mk_hilo(float4v f0, float4v f1, short8v& hv, short8v& lv) {
  frag_cast h, lo;
  float a0 = f0[0], a1 = f0[1], a2 = f0[2], a3 = f0[3];
  float a4 = f1[0], a5 = f1[1], a6 = f1[2], a7 = f1[3];
  h.u[0] = packtrunc(a0, a1); h.u[1] = packtrunc(a2, a3);
  h.u[2] = packtrunc(a4, a5); h.u[3] = packtrunc(a6, a7);
  lo.u[0] = packrn(a0 - trunchi(a0), a1 - trunchi(a1));
  lo.u[1] = packrn(a2 - trunchi(a2), a3 - trunchi(a3));
  lo.u[2] = packrn(a4 - trunchi(a4), a5 - trunchi(a5));
  lo.u[3] = packrn(a6 - trunchi(a6), a7 - trunchi(a7));
  hv = h.s; lv = lo.s;
}

// ---------------- Path A pre-kernels (unchanged) ----------------
__global__ __launch_bounds__(256) void conv_k(const float* __restrict__ prefix_k,
                                              const float* __restrict__ key,
                                              unsigned short* __restrict__ k_hi,
                                              unsigned short* __restrict__ k_lo) {
  int id = blockIdx.x * 256 + threadIdx.x;
  int chunk = id & 127;
  int row = id >> 7;
  int b = row / LPAD;
  int n = row - b * LPAD;
  int col = chunk * 8;
  float4v f0 = {0.f, 0.f, 0.f, 0.f}, f1 = {0.f, 0.f, 0.f, 0.f};
  if (n < LL) {
    const float* src = (n < PP) ? (prefix_k + (size_t)n * HH + col)
                                : (key + ((size_t)b * SS + (n - PP)) * HH + col);
    f0 = *(const float4v*)src;
    f1 = *(const float4v*)(src + 4);
  }
  short8v hv, lv;
  mk_hilo(f0, f1, hv, lv);
  size_t off = (size_t)row * HH + col;
  *(short8v*)(k_hi + off) = hv;
  *(short8v*)(k_lo + off) = lv;
}

__global__ __launch_bounds__(256) void conv_v(const float* __restrict__ prefix_v,
                                              const float* __restrict__ value,
                                              unsigned short* __restrict__ v_t) {
  __shared__ float tile[32][68];
  int nt = blockIdx.x, dt = blockIdx.y, b = blockIdx.z;
  int t = threadIdx.x;
  #pragma unroll
  for (int p = 0; p < 2; ++p) {
    int nl = p * 16 + (t >> 4);
    int n = nt * 32 + nl;
    int d = dt * 64 + (t & 15) * 4;
    float4v f = {0.f, 0.f, 0.f, 0.f};
    if (n < LL) {
      const float* src = (n < PP) ? (prefix_v + (size_t)n * HH + d)
                                  : (value + ((size_t)b * SS + (n - PP)) * HH + d);
      f = *(const float4v*)src;
    }
    *(float4v*)&tile[nl][(t & 15) * 4] = f;
  }
  __syncthreads();
  int dl = t >> 2;
  int nch = (t & 3) * 8;
  uint4v outv;
  #pragma unroll
  for (int j = 0; j < 4; ++j)
    outv[j] = packrn(tile[nch + 2 * j][dl], tile[nch + 2 * j + 1][dl]);
  size_t off = ((size_t)b * HH + dt * 64 + dl) * LPAD + nt * 32 + nch;
  frag_cast fc; fc.u = outv;
  *(short8v*)(v_t + off) = fc.s;
}

// ---------------- fused flash attention, v2 ----------------
// 8 waves/WG. Wave w: row-group rg=w&1 (16 Q rows), D-slice ds=w>>2? no: ds=w>>1
// (256 dims). Per KV tile (N=32): each wave computes partial S(16x32) over its
// 256 dims -> LDS (double-buffered) -> ONE barrier -> every wave redundantly
// reduces its row-group's 4 partials, does softmax fully in registers, packs P
// into the MFMA A-fragment, and runs PV over its D-slice. m/l/sc never touch LDS.
template<int PATH>
__global__ __launch_bounds__(512, 2) void attn_fused(
    const float* __restrict__ q,
    const float* __restrict__ key,
    const float* __restrict__ value,
    const float* __restrict__ prefix_k,
    const float* __restrict__ prefix_v,
    const unsigned short* __restrict__ k_hi,
    const unsigned short* __restrict__ k_lo,
    const unsigned short* __restrict__ v_t,
    float* __restrict__ out)
{
  // [bank][wave][qrow 0..15][kvcol 0..31 +4 pad]; stride 36 words = 144 B
  // (16B-aligned rows; b128 reads land 8 lanes/4-bank group = conflict-free)
  __shared__ __align__(16) float buf[2][8][16][36];   // 36864 B

  const int tid = threadIdx.x;
  const int w  = tid >> 6;
  const int ln = tid & 63;
  const int g  = ln >> 4;     // 16-lane group 0..3
  const int li = ln & 15;
  const int rg = w & 1;       // row-group: Q rows rg*16 .. +16
  const int ds = w >> 1;      // D-slice: dims ds*256 .. +256
  const int dbase = ds * 256;

  // XCD-aware mapping: batch b pinned to XCDs {2b,2b+1}
  const int bid = blockIdx.x;
  const int xcd = bid & 7;
  const int b = xcd >> 1;
  const int qt = ((bid >> 3) << 1) | (xcd & 1);   // 0..127
  const int q0 = qt * 32;

  // Q fragments (hi/lo): A-layout row = li, k = g*8+j; kt covers 256 dims
  short8v qhi[8], qlo[8];
  #pragma unroll
  for (int kt = 0; kt < 8; ++kt) {
    const float* p = q + ((size_t)(b * SS + q0 + rg * 16 + li)) * HH + dbase + kt * 32 + g * 8;
    mk_hilo(*(const float4v*)p, *(const float4v*)(p + 4), qhi[kt], qlo[kt]);
  }

  float4v z4 = {0.f, 0.f, 0.f, 0.f};
  float4v o[16];
  #pragma unroll
  for (int dt = 0; dt < 16; ++dt) o[dt] = z4;
  float m_r = -1e30f, l_r = 0.f;

  for (int it = 0; it < NTILES; ++it) {
    const int n0 = it * 32;
    const int bk = it & 1;

    // ---- phase 1: partial QK^T (bf16x3) over this wave's 256 dims ----
    float4v sacc[2];
    sacc[0] = z4; sacc[1] = z4;
    #pragma unroll
    for (int kt = 0; kt < 8; ++kt) {
      short8v kh[2], klo2[2];
      #pragma unroll
      for (int nt = 0; nt < 2; ++nt) {
        const int n = n0 + nt * 16 + li;
        if constexpr (PATH == 0) {
          size_t off = ((size_t)(b * LPAD + n)) * HH + dbase + kt * 32 + g * 8;
          kh[nt]   = *(const short8v*)(k_hi + off);
          klo2[nt] = *(const short8v*)(k_lo + off);
        } else {
          const int nc = (n < LL) ? n : 0;
          const float* kp = (nc < PP) ? (prefix_k + (size_t)nc * HH)
                                      : (key + ((size_t)b * SS + (nc - PP)) * HH);
          kp += dbase + kt * 32 + g * 8;
          mk_hilo(*(const float4v*)kp, *(const float4v*)(kp + 4), kh[nt], klo2[nt]);
        }
      }
      #pragma unroll
      for (int nt = 0; nt < 2; ++nt) {
        sacc[nt] = __builtin_amdgcn_mfma_f32_16x16x32_bf16(qhi[kt], kh[nt],   sacc[nt], 0, 0, 0);
        sacc[nt] = __builtin_amdgcn_mfma_f32_16x16x32_bf16(qhi[kt], klo2[nt], sacc[nt], 0, 0, 0);
        sacc[nt] = __builtin_amdgcn_mfma_f32_16x16x32_bf16(qlo[kt], kh[nt],   sacc[nt], 0, 0, 0);
      }
    }
    // C/D layout: qrow = g*4+r, kvcol = nt*16+li  -> store [qrow][kvcol]
    #pragma unroll
    for (int nt = 0; nt < 2; ++nt)
      #pragma unroll
      for (int r = 0; r < 4; ++r)
        buf[bk][w][g * 4 + r][nt * 16 + li] = sacc[nt][r];
    __syncthreads();   // the ONLY barrier per tile

    // ---- phase 2 (per-wave, independent): reduce 4 partials for own rows ----
    // lane (g,li) owns S[row=li][cols g*8 .. g*8+8)  == A-fragment layout
    float4v a0 = z4, a1 = z4;
    #pragma unroll
    for (int i = 0; i < 4; ++i) {
      const float4v* pp = (const float4v*)&buf[bk][rg + 2 * i][li][g * 8];
      a0 += pp[0];
      a1 += pp[1];
    }
    float s0[8];
    s0[0] = a0[0]; s0[1] = a0[1]; s0[2] = a0[2]; s0[3] = a0[3];
    s0[4] = a1[0]; s0[5] = a1[1]; s0[6] = a1[2]; s0[7] = a1[3];

    // V prefetch for first half of D-slice (issue before softmax VALU)
    short8v vf[8];
    if constexpr (PATH == 0) {
      #pragma unroll
      for (int dt = 0; dt < 8; ++dt) {
        size_t off = ((size_t)(b * HH) + dbase + dt * 16 + li) * LPAD + n0 + g * 8;
        vf[dt] = *(const short8v*)(v_t + off);
      }
    }

    if constexpr (PATH == 1) {
      #pragma unroll
      for (int j = 0; j < 8; ++j)
        if (n0 + g * 8 + j >= LL) s0[j] = -1e30f;
    }

    // ---- softmax, fully in registers (replicated across the 4 D-waves) ----
    float tmax = fmaxf(fmaxf(fmaxf(s0[0], s0[1]), fmaxf(s0[2], s0[3])),
                       fmaxf(fmaxf(s0[4], s0[5]), fmaxf(s0[6], s0[7])));
    tmax = fmaxf(tmax, __shfl_xor(tmax, 16));
    tmax = fmaxf(tmax, __shfl_xor(tmax, 32));
    const float m_new = fmaxf(m_r, tmax);
    const float sc = exp2f((m_r - m_new) * LOG2E);
    float p[8];
    #pragma unroll
    for (int j = 0; j < 8; ++j) p[j] = exp2f((s0[j] - m_new) * LOG2E);
    float ts = ((p[0] + p[1]) + (p[2] + p[3])) + ((p[4] + p[5]) + (p[6] + p[7]));
    ts += __shfl_xor(ts, 16);
    ts += __shfl_xor(ts, 32);
    l_r = l_r * sc + ts;
    m_r = m_new;

    // redistribute sc from row-layout (li) to C-layout rows (g*4+r)
    float sc_c[4];
    #pragma unroll
    for (int r = 0; r < 4; ++r) sc_c[r] = __shfl(sc, g * 4 + r);

    // rescale O
    #pragma unroll
    for (int dt = 0; dt < 16; ++dt)
      #pragma unroll
      for (int r = 0; r < 4; ++r)
        o[dt][r] *= sc_c[r];

    // pack P -> bf16 A-fragment (already in the right lane layout)
    frag_cast pc;
    pc.u[0] = packrn(p[0], p[1]); pc.u[1] = packrn(p[2], p[3]);
    pc.u[2] = packrn(p[4], p[5]); pc.u[3] = packrn(p[6], p[7]);
    short8v pa = pc.s;

    // ---- phase 3: PV over this wave's 256 dims ----
    #pragma unroll
    for (int dt = 0; dt < 16; ++dt) {
      short8v vb;
      if constexpr (PATH == 0) {
        if (dt < 8) {
          vb = vf[dt];
        } else {
          size_t off = ((size_t)(b * HH) + dbase + dt * 16 + li) * LPAD + n0 + g * 8;
          vb = *(const short8v*)(v_t + off);
        }
      } else {
        frag_cast fc;
        const int d = dbase + dt * 16 + li;
        #pragma unroll
        for (int jj = 0; jj < 4; ++jj) {
          int na = n0 + g * 8 + jj * 2;
          int nb2 = na + 1;
          int nca = (na < LL) ? na : 0;
          int ncb = (nb2 < LL) ? nb2 : 0;
          const float* pva = (nca < PP) ? (prefix_v + (size_t)nca * HH + d)
                                        : (value + ((size_t)b * SS + (nca - PP)) * HH + d);
          const float* pvb = (ncb < PP) ? (prefix_v + (size_t)ncb * HH + d)
                                        : (value + ((size_t)b * SS + (ncb - PP)) * HH + d);
          fc.u[jj] = packrn(*pva, *pvb);
        }
        vb = fc.s;
      }
      o[dt] = __builtin_amdgcn_mfma_f32_16x16x32_bf16(pa, vb, o[dt], 0, 0, 0);
    }
    // no second barrier: next tile writes the OTHER buf bank
  }

  // ---- finalize ----
  float il[4];
  #pragma unroll
  for (int r = 0; r < 4; ++r) il[r] = 1.0f / __shfl(l_r, g * 4 + r);
  #pragma unroll
  for (int dt = 0; dt < 16; ++dt)
    #pragma unroll
    for (int r = 0; r < 4; ++r)
      out[((size_t)(b * SS + q0 + rg * 16 + g * 4 + r)) * HH + dbase + dt * 16 + li]
          = o[dt][r] * il[r];
}

extern "C" void kernel_launch(void* const* d_in, const int* in_sizes, int n_in,
                              void* d_out, int out_size, void* d_ws, size_t ws_size,
                              hipStream_t stream) {
  const float* q        = (const float*)d_in[0];
  const float* key      = (const float*)d_in[1];
  const float* value    = (const float*)d_in[2];
  const float* prefix_k = (const float*)d_in[3];
  const float* prefix_v = (const float*)d_in[4];
  float* out = (float*)d_out;

  const size_t PLANE = (size_t)BB * LPAD * HH;
  const size_t NEED  = 3 * PLANE * sizeof(unsigned short);

  if (ws_size >= NEED) {
    unsigned short* k_hi = (unsigned short*)d_ws;
    unsigned short* k_lo = k_hi + PLANE;
    unsigned short* v_t  = k_lo + PLANE;
    conv_k<<<(BB * LPAD * 128) / 256, 256, 0, stream>>>(prefix_k, key, k_hi, k_lo);
    conv_v<<<dim3(NTILES, 16, BB), 256, 0, stream>>>(prefix_v, value, v_t);
    attn_fused<0><<<512, 512, 0, stream>>>(q, key, value, prefix_k, prefix_v,
                                           k_hi, k_lo, v_t, out);
  } else {
    attn_fused<1><<<512, 512, 0, stream>>>(q, key, value, prefix_k, prefix_v,
                                           nullptr, nullptr, nullptr, out);
  }
}

// Round 3
// 509.768 us; speedup vs baseline: 5.5414x; 5.5414x over previous
//
#include <hip/hip_runtime.h>
#include <cstdint>
#include <cstddef>

// Problem constants
#define BB 4
#define SS 4096
#define HH 1024
#define PP 10
#define LL 4106              // P + S
#define LPAD 4128            // 129 * 32
#define NTILES 129
#define CHUNKS_PB (NTILES * 4096)   // 16B-chunks per batch plane (= 528384)
#define LOG2E 1.44269504088896f

typedef __attribute__((ext_vector_type(8))) _Float16 half8v;  // 4 VGPR MFMA frag
typedef __attribute__((ext_vector_type(4))) float float4v;

union hu16 { _Float16 h; unsigned short u; };

__device__ __forceinline__ half8v cvt8h(float4v f0, float4v f1) {
  half8v h;
  h[0] = (_Float16)f0[0]; h[1] = (_Float16)f0[1];
  h[2] = (_Float16)f0[2]; h[3] = (_Float16)f0[3];
  h[4] = (_Float16)f1[0]; h[5] = (_Float16)f1[1];
  h[6] = (_Float16)f1[2]; h[7] = (_Float16)f1[3];
  return h;
}
__device__ __forceinline__ unsigned pack2h(float a, float b) {
  hu16 x, y; x.h = (_Float16)a; y.h = (_Float16)b;
  return (unsigned)x.u | ((unsigned)y.u << 16);
}

// raw barrier: drain own LDS ops, no vmcnt drain (keeps global loads in flight)
#define LGKM_BAR() do { \
  asm volatile("s_waitcnt lgkmcnt(0)" ::: "memory"); \
  __builtin_amdgcn_s_barrier(); \
  asm volatile("" ::: "memory"); } while (0)

// ---------- pre-kernels: fp16 planes in MFMA-fragment order ----------
// K chunk id = (((it*2+nt)*32+kt')*4+g)*16+li ; holds K[n=it*32+nt*16+li][d=kt'*32+g*8 ..+8)
__global__ __launch_bounds__(256) void conv_k(const float* __restrict__ prefix_k,
                                              const float* __restrict__ key,
                                              _Float16* __restrict__ kp) {
  const int b = blockIdx.y;
  const int id = blockIdx.x * 256 + threadIdx.x;       // < CHUNKS_PB
  const int li = id & 15, g = (id >> 4) & 3, ktp = (id >> 6) & 31,
            nt = (id >> 11) & 1, it = id >> 12;
  const int n = it * 32 + nt * 16 + li;
  const int d = ktp * 32 + g * 8;
  float4v f0 = {0.f, 0.f, 0.f, 0.f}, f1 = {0.f, 0.f, 0.f, 0.f};
  if (n < LL) {
    const float* src = (n < PP) ? prefix_k + (size_t)n * HH + d
                                : key + ((size_t)b * SS + (n - PP)) * HH + d;
    f0 = *(const float4v*)src; f1 = *(const float4v*)(src + 4);
  }
  *(half8v*)(kp + ((size_t)b * CHUNKS_PB + id) * 8) = cvt8h(f0, f1);
}

// V chunk id = (it*4+g)*1024 + d ; holds V[n=it*32+g*8 ..+8)][d] along n
__global__ __launch_bounds__(256) void conv_v(const float* __restrict__ prefix_v,
                                              const float* __restrict__ value,
                                              _Float16* __restrict__ vp) {
  const int b = blockIdx.y;
  const int id = blockIdx.x * 256 + threadIdx.x;
  const int d = id & 1023, g = (id >> 10) & 3, it = id >> 12;
  const int nb = it * 32 + g * 8;
  half8v h;
  #pragma unroll
  for (int j = 0; j < 8; ++j) {
    int n = nb + j;
    float f = 0.f;
    if (n < LL)
      f = (n < PP) ? prefix_v[(size_t)n * HH + d]
                   : value[((size_t)b * SS + (n - PP)) * HH + d];
    h[j] = (_Float16)f;
  }
  *(half8v*)(vp + ((size_t)b * CHUNKS_PB + id) * 8) = h;
}

// ---------------- fused flash attention, v3 ----------------
// 8 waves; wave w owns D-slice [128w,128w+128), all M=32 rows. KV tile 32.
// A: [issue V(t)] QK (fp16, 16 MFMA) -> S partials to LDS; raw barrier
// B: [issue K(t+1)] per-wave slab softmax (rows 4w..4w+3) -> P fp16 + sc; raw barrier
// C: rescale O; PV (16 MFMA). Global loads stay in flight across barriers.
template<int PATH>
__global__ __launch_bounds__(512, 2) void attn_fused(
    const float* __restrict__ q,
    const float* __restrict__ key,
    const float* __restrict__ value,
    const float* __restrict__ prefix_k,
    const float* __restrict__ prefix_v,
    const _Float16* __restrict__ kp,
    const _Float16* __restrict__ vp,
    float* __restrict__ out)
{
  __shared__ __align__(16) float sbuf[8][32][36];       // 36.9 KB partial S
  __shared__ __align__(16) unsigned short Pl[32][40];   // P fp16
  __shared__ float sc_l[32];
  __shared__ float l_l[32];

  const int tid = threadIdx.x;
  const int w = tid >> 6, ln = tid & 63, g = ln >> 4, li = ln & 15;
  const int bid = blockIdx.x, xcd = bid & 7, b = xcd >> 1;
  const int qt = ((bid >> 3) << 1) | (xcd & 1);
  const int q0 = qt * 32;
  const int dbase = w * 128;

  // Q fragments fp16: A-layout row=li, k=g*8+j
  half8v qf[2][4];
  #pragma unroll
  for (int mt = 0; mt < 2; ++mt)
    #pragma unroll
    for (int kt = 0; kt < 4; ++kt) {
      const float* p = q + ((size_t)(b * SS + q0 + mt * 16 + li)) * HH + dbase + kt * 32 + g * 8;
      qf[mt][kt] = cvt8h(*(const float4v*)p, *(const float4v*)(p + 4));
    }

  float4v z4 = {0.f, 0.f, 0.f, 0.f};
  float4v o[2][8];
  #pragma unroll
  for (int mt = 0; mt < 2; ++mt)
    #pragma unroll
    for (int dt = 0; dt < 8; ++dt) o[mt][dt] = z4;
  float m_r = -1e30f, l_r = 0.f;

  const _Float16* kbase = kp + ((size_t)b * CHUNKS_PB + (size_t)(w * 4) * 64 + g * 16 + li) * 8;
  const _Float16* vbase = vp + ((size_t)b * CHUNKS_PB + (size_t)g * 1024 + dbase + li) * 8;

  half8v kreg[8];   // [kt*2+nt]
  if constexpr (PATH == 0) {
    #pragma unroll
    for (int kt = 0; kt < 4; ++kt)
      #pragma unroll
      for (int nt = 0; nt < 2; ++nt)
        kreg[kt * 2 + nt] = *(const half8v*)(kbase + (size_t)(nt * 2048 + kt * 64) * 8);
  }

  const int srow = w * 4 + (ln >> 4);     // slab row this lane helps with
  const int c0 = (ln & 15) * 2;

  for (int it = 0; it < NTILES; ++it) {
    // ---- phase A ----
    half8v vreg[8];
    if constexpr (PATH == 0) {
      #pragma unroll
      for (int dt = 0; dt < 8; ++dt)
        vreg[dt] = *(const half8v*)(vbase + (size_t)(dt * 16) * 8);
    }
    float4v sacc[2][2];
    sacc[0][0] = z4; sacc[0][1] = z4; sacc[1][0] = z4; sacc[1][1] = z4;
    __builtin_amdgcn_s_setprio(1);
    #pragma unroll
    for (int kt = 0; kt < 4; ++kt) {
      half8v kb[2];
      if constexpr (PATH == 0) {
        kb[0] = kreg[kt * 2 + 0]; kb[1] = kreg[kt * 2 + 1];
      } else {
        #pragma unroll
        for (int nt = 0; nt < 2; ++nt) {
          int n = it * 32 + nt * 16 + li;
          int nc = (n < LL) ? n : 0;
          const float* kpp = (nc < PP) ? (prefix_k + (size_t)nc * HH)
                                       : (key + ((size_t)b * SS + (nc - PP)) * HH);
          kpp += dbase + kt * 32 + g * 8;
          kb[nt] = cvt8h(*(const float4v*)kpp, *(const float4v*)(kpp + 4));
        }
      }
      #pragma unroll
      for (int mt = 0; mt < 2; ++mt)
        #pragma unroll
        for (int nt = 0; nt < 2; ++nt)
          sacc[mt][nt] = __builtin_amdgcn_mfma_f32_16x16x32_f16(qf[mt][kt], kb[nt], sacc[mt][nt], 0, 0, 0);
    }
    __builtin_amdgcn_s_setprio(0);
    // C/D: row = g*4+r, col = li
    #pragma unroll
    for (int mt = 0; mt < 2; ++mt)
      #pragma unroll
      for (int nt = 0; nt < 2; ++nt)
        #pragma unroll
        for (int r = 0; r < 4; ++r)
          sbuf[w][mt * 16 + g * 4 + r][nt * 16 + li] = sacc[mt][nt][r];
    LGKM_BAR();

    // ---- phase B ----
    if constexpr (PATH == 0) {
      kbase += (size_t)4096 * 8;          // next tile (last iter: benign in-plane overrun)
      #pragma unroll
      for (int kt = 0; kt < 4; ++kt)
        #pragma unroll
        for (int nt = 0; nt < 2; ++nt)
          kreg[kt * 2 + nt] = *(const half8v*)(kbase + (size_t)(nt * 2048 + kt * 64) * 8);
    }
    {
      float s0 = 0.f, s1 = 0.f;
      #pragma unroll
      for (int i = 0; i < 8; ++i) {
        float2 t = *(const float2*)&sbuf[i][srow][c0];
        s0 += t.x; s1 += t.y;
      }
      if constexpr (PATH == 1) {
        if (it * 32 + c0 >= LL)     s0 = -1e30f;
        if (it * 32 + c0 + 1 >= LL) s1 = -1e30f;
      }
      float mx = fmaxf(s0, s1);
      mx = fmaxf(mx, __shfl_xor(mx, 1));
      mx = fmaxf(mx, __shfl_xor(mx, 2));
      mx = fmaxf(mx, __shfl_xor(mx, 4));
      mx = fmaxf(mx, __shfl_xor(mx, 8));
      const float m_new = fmaxf(m_r, mx);
      const float scp = exp2f((m_r - m_new) * LOG2E);
      const float p0 = exp2f((s0 - m_new) * LOG2E);
      const float p1 = exp2f((s1 - m_new) * LOG2E);
      float ts = p0 + p1;
      ts += __shfl_xor(ts, 1);
      ts += __shfl_xor(ts, 2);
      ts += __shfl_xor(ts, 4);
      ts += __shfl_xor(ts, 8);
      l_r = l_r * scp + ts;
      m_r = m_new;
      *(unsigned*)&Pl[srow][c0] = pack2h(p0, p1);
      if ((ln & 15) == 0) sc_l[srow] = scp;
    }
    LGKM_BAR();

    // ---- phase C ----
    float scc[2][4];
    #pragma unroll
    for (int mt = 0; mt < 2; ++mt)
      #pragma unroll
      for (int r = 0; r < 4; ++r)
        scc[mt][r] = sc_l[mt * 16 + g * 4 + r];
    #pragma unroll
    for (int mt = 0; mt < 2; ++mt)
      #pragma unroll
      for (int dt = 0; dt < 8; ++dt)
        #pragma unroll
        for (int r = 0; r < 4; ++r)
          o[mt][dt][r] *= scc[mt][r];

    half8v pa0 = *(const half8v*)&Pl[li][g * 8];
    half8v pa1 = *(const half8v*)&Pl[16 + li][g * 8];
    __builtin_amdgcn_s_setprio(1);
    #pragma unroll
    for (int dt = 0; dt < 8; ++dt) {
      half8v vb;
      if constexpr (PATH == 0) {
        vb = vreg[dt];
      } else {
        const int d = dbase + dt * 16 + li;
        #pragma unroll
        for (int j = 0; j < 8; ++j) {
          int n = it * 32 + g * 8 + j;
          int nc = (n < LL) ? n : 0;    // clamped rows have P==0
          float f = (nc < PP) ? prefix_v[(size_t)nc * HH + d]
                              : value[((size_t)b * SS + (nc - PP)) * HH + d];
          vb[j] = (_Float16)f;
        }
      }
      o[0][dt] = __builtin_amdgcn_mfma_f32_16x16x32_f16(pa0, vb, o[0][dt], 0, 0, 0);
      o[1][dt] = __builtin_amdgcn_mfma_f32_16x16x32_f16(pa1, vb, o[1][dt], 0, 0, 0);
    }
    __builtin_amdgcn_s_setprio(0);
    if constexpr (PATH == 0) vbase += (size_t)4096 * 8;
  }

  // ---- finalize ----
  if ((ln & 15) == 0) l_l[srow] = l_r;
  LGKM_BAR();
  float il[2][4];
  #pragma unroll
  for (int mt = 0; mt < 2; ++mt)
    #pragma unroll
    for (int r = 0; r < 4; ++r)
      il[mt][r] = 1.0f / l_l[mt * 16 + g * 4 + r];
  #pragma unroll
  for (int mt = 0; mt < 2; ++mt)
    #pragma unroll
    for (int dt = 0; dt < 8; ++dt)
      #pragma unroll
      for (int r = 0; r < 4; ++r)
        out[((size_t)(b * SS + q0 + mt * 16 + g * 4 + r)) * HH + dbase + dt * 16 + li]
            = o[mt][dt][r] * il[mt][r];
}

extern "C" void kernel_launch(void* const* d_in, const int* in_sizes, int n_in,
                              void* d_out, int out_size, void* d_ws, size_t ws_size,
                              hipStream_t stream) {
  const float* q        = (const float*)d_in[0];
  const float* key      = (const float*)d_in[1];
  const float* value    = (const float*)d_in[2];
  const float* prefix_k = (const float*)d_in[3];
  const float* prefix_v = (const float*)d_in[4];
  float* out = (float*)d_out;

  const size_t PLANE = (size_t)BB * CHUNKS_PB * 8;              // fp16 elems per plane
  const size_t NEED  = 2 * PLANE * sizeof(unsigned short);      // 67.6 MB

  if (ws_size >= NEED) {
    _Float16* kp = (_Float16*)d_ws;
    _Float16* vp = kp + PLANE;
    conv_k<<<dim3(CHUNKS_PB / 256, BB), 256, 0, stream>>>(prefix_k, key, kp);
    conv_v<<<dim3(CHUNKS_PB / 256, BB), 256, 0, stream>>>(prefix_v, value, vp);
    attn_fused<0><<<512, 512, 0, stream>>>(q, key, value, prefix_k, prefix_v, kp, vp, out);
  } else {
    attn_fused<1><<<512, 512, 0, stream>>>(q, key, value, prefix_k, prefix_v,
                                           nullptr, nullptr, out);
  }
}

// Round 4
// 472.649 us; speedup vs baseline: 5.9766x; 1.0785x over previous
//
#include <hip/hip_runtime.h>
#include <cstdint>
#include <cstddef>

// Problem constants
#define BB 4
#define SS 4096
#define HH 1024
#define PP 10
#define LL 4106              // P + S
#define NTILES 129
#define CHUNKS_PB (NTILES * 4096)   // 16B-chunks per batch plane (= 528384)
#define TILE_ELEMS (4096 * 8)       // fp16 elems per tile in a plane
#define LOG2E 1.44269504088896f

typedef __attribute__((ext_vector_type(8))) _Float16 half8v;  // 4 VGPR MFMA frag
typedef __attribute__((ext_vector_type(4))) float float4v;

union hu16 { _Float16 h; unsigned short u; };

__device__ __forceinline__ half8v cvt8h(float4v f0, float4v f1) {
  half8v h;
  h[0] = (_Float16)f0[0]; h[1] = (_Float16)f0[1];
  h[2] = (_Float16)f0[2]; h[3] = (_Float16)f0[3];
  h[4] = (_Float16)f1[0]; h[5] = (_Float16)f1[1];
  h[6] = (_Float16)f1[2]; h[7] = (_Float16)f1[3];
  return h;
}
__device__ __forceinline__ unsigned pack2h(float a, float b) {
  hu16 x, y; x.h = (_Float16)a; y.h = (_Float16)b;
  return (unsigned)x.u | ((unsigned)y.u << 16);
}

// raw barrier: drain own LDS ops, no vmcnt drain (keeps global loads in flight)
#define LGKM_BAR() do { \
  asm volatile("s_waitcnt lgkmcnt(0)" ::: "memory"); \
  __builtin_amdgcn_s_barrier(); \
  asm volatile("" ::: "memory"); } while (0)

// ---------- pre-kernels: fp16 planes in MFMA-fragment order ----------
__global__ __launch_bounds__(256) void conv_k(const float* __restrict__ prefix_k,
                                              const float* __restrict__ key,
                                              _Float16* __restrict__ kp) {
  const int b = blockIdx.y;
  const int id = blockIdx.x * 256 + threadIdx.x;       // < CHUNKS_PB
  const int li = id & 15, g = (id >> 4) & 3, ktp = (id >> 6) & 31,
            nt = (id >> 11) & 1, it = id >> 12;
  const int n = it * 32 + nt * 16 + li;
  const int d = ktp * 32 + g * 8;
  float4v f0 = {0.f, 0.f, 0.f, 0.f}, f1 = {0.f, 0.f, 0.f, 0.f};
  if (n < LL) {
    const float* src = (n < PP) ? prefix_k + (size_t)n * HH + d
                                : key + ((size_t)b * SS + (n - PP)) * HH + d;
    f0 = *(const float4v*)src; f1 = *(const float4v*)(src + 4);
  }
  *(half8v*)(kp + ((size_t)b * CHUNKS_PB + id) * 8) = cvt8h(f0, f1);
}

__global__ __launch_bounds__(256) void conv_v(const float* __restrict__ prefix_v,
                                              const float* __restrict__ value,
                                              _Float16* __restrict__ vp) {
  const int b = blockIdx.y;
  const int id = blockIdx.x * 256 + threadIdx.x;
  const int d = id & 1023, g = (id >> 10) & 3, it = id >> 12;
  const int nb = it * 32 + g * 8;
  half8v h;
  #pragma unroll
  for (int j = 0; j < 8; ++j) {
    int n = nb + j;
    float f = 0.f;
    if (n < LL)
      f = (n < PP) ? prefix_v[(size_t)n * HH + d]
                   : value[((size_t)b * SS + (n - PP)) * HH + d];
    h[j] = (_Float16)f;
  }
  *(half8v*)(vp + ((size_t)b * CHUNKS_PB + id) * 8) = h;
}

// ---------------- fused flash attention, v4: 1-barrier/iter pipeline ----------------
// 8 waves; wave w owns D-slice [128w,128w+128), M=32 rows. KV tile 32.
// iter i: QK(i)->sbuf[i&1]; kreg<-K(i+1); softmax(i-1) sbuf[(i-1)&1]->Pl/sc[(i-1)&1];
//         rescale+PV(i-2) from Pl/sc[i&1], vreg=V(i-2); vreg<-V(i-1); BAR.
template<int PATH>
__global__ __launch_bounds__(512, 2) void attn_fused(
    const float* __restrict__ q,
    const float* __restrict__ key,
    const float* __restrict__ value,
    const float* __restrict__ prefix_k,
    const float* __restrict__ prefix_v,
    const _Float16* __restrict__ kp,
    const _Float16* __restrict__ vp,
    float* __restrict__ out)
{
  __shared__ __align__(16) float sbuf[2][8][32][36];     // 73.7 KB, double-banked
  __shared__ __align__(16) unsigned short Pl[2][32][40]; // 5.1 KB
  __shared__ float sc_l[2][32];
  __shared__ float l_l[32];

  const int tid = threadIdx.x;
  const int w = tid >> 6, ln = tid & 63, g = ln >> 4, li = ln & 15;
  const int bid = blockIdx.x, xcd = bid & 7, b = xcd >> 1;
  const int qt = ((bid >> 3) << 1) | (xcd & 1);
  const int q0 = qt * 32;
  const int dbase = w * 128;

  // Q fragments fp16: A-layout row=li, k=g*8+j
  half8v qf[2][4];
  #pragma unroll
  for (int mt = 0; mt < 2; ++mt)
    #pragma unroll
    for (int kt = 0; kt < 4; ++kt) {
      const float* p = q + ((size_t)(b * SS + q0 + mt * 16 + li)) * HH + dbase + kt * 32 + g * 8;
      qf[mt][kt] = cvt8h(*(const float4v*)p, *(const float4v*)(p + 4));
    }

  float4v z4 = {0.f, 0.f, 0.f, 0.f};
  float4v o[2][8];
  #pragma unroll
  for (int mt = 0; mt < 2; ++mt)
    #pragma unroll
    for (int dt = 0; dt < 8; ++dt) o[mt][dt] = z4;
  float m_r = -1e30f, l_r = 0.f;

  const _Float16* kbase = kp + ((size_t)b * CHUNKS_PB + (size_t)(w * 4) * 64 + g * 16 + li) * 8;
  const _Float16* vbase = vp + ((size_t)b * CHUNKS_PB + (size_t)g * 1024 + dbase + li) * 8;

  half8v kreg[8];   // K(i) during iter i
  half8v vreg[8];   // V(i-2) during iter i
  if constexpr (PATH == 0) {
    #pragma unroll
    for (int kt = 0; kt < 4; ++kt)
      #pragma unroll
      for (int nt = 0; nt < 2; ++nt)
        kreg[kt * 2 + nt] = *(const half8v*)(kbase + (size_t)(nt * 2048 + kt * 64) * 8);
  }

  const int srow = w * 4 + (ln >> 4);     // slab row this lane helps with
  const int c0 = (ln & 15) * 2;

  for (int i = 0; i < NTILES + 2; ++i) {
    const int sb = i & 1;        // sbuf bank written by QK(i); Pl/sc bank read by PV(i-2)
    const int ob = sb ^ 1;       // sbuf bank read by softmax(i-1); Pl/sc bank it writes

    // ---- QK(i) ----
    if (i < NTILES) {
      float4v sacc[2][2];
      sacc[0][0] = z4; sacc[0][1] = z4; sacc[1][0] = z4; sacc[1][1] = z4;
      __builtin_amdgcn_s_setprio(1);
      #pragma unroll
      for (int kt = 0; kt < 4; ++kt) {
        half8v kb[2];
        if constexpr (PATH == 0) {
          kb[0] = kreg[kt * 2 + 0]; kb[1] = kreg[kt * 2 + 1];
        } else {
          #pragma unroll
          for (int nt = 0; nt < 2; ++nt) {
            int n = i * 32 + nt * 16 + li;
            int nc = (n < LL) ? n : 0;
            const float* kpp = (nc < PP) ? (prefix_k + (size_t)nc * HH)
                                         : (key + ((size_t)b * SS + (nc - PP)) * HH);
            kpp += dbase + kt * 32 + g * 8;
            kb[nt] = cvt8h(*(const float4v*)kpp, *(const float4v*)(kpp + 4));
          }
        }
        #pragma unroll
        for (int mt = 0; mt < 2; ++mt)
          #pragma unroll
          for (int nt = 0; nt < 2; ++nt)
            sacc[mt][nt] = __builtin_amdgcn_mfma_f32_16x16x32_f16(qf[mt][kt], kb[nt], sacc[mt][nt], 0, 0, 0);
      }
      __builtin_amdgcn_s_setprio(0);
      // C/D: row = g*4+r, col = li
      #pragma unroll
      for (int mt = 0; mt < 2; ++mt)
        #pragma unroll
        for (int nt = 0; nt < 2; ++nt)
          #pragma unroll
          for (int r = 0; r < 4; ++r)
            sbuf[sb][w][mt * 16 + g * 4 + r][nt * 16 + li] = sacc[mt][nt][r];
      // reload kreg <- K(i+1)  (benign 1-tile overrun into vp at the end of plane)
      if constexpr (PATH == 0) {
        kbase += TILE_ELEMS;
        #pragma unroll
        for (int kt = 0; kt < 4; ++kt)
          #pragma unroll
          for (int nt = 0; nt < 2; ++nt)
            kreg[kt * 2 + nt] = *(const half8v*)(kbase + (size_t)(nt * 2048 + kt * 64) * 8);
      }
    }

    // ---- softmax(i-1) ----
    if (i >= 1 && i <= NTILES) {
      const int t = i - 1;
      float s0 = 0.f, s1 = 0.f;
      #pragma unroll
      for (int bw = 0; bw < 8; ++bw) {
        float2 tv = *(const float2*)&sbuf[ob][bw][srow][c0];
        s0 += tv.x; s1 += tv.y;
      }
      if constexpr (PATH == 1) {
        if (t * 32 + c0 >= LL)     s0 = -1e30f;
        if (t * 32 + c0 + 1 >= LL) s1 = -1e30f;
      }
      float mx = fmaxf(s0, s1);
      mx = fmaxf(mx, __shfl_xor(mx, 1));
      mx = fmaxf(mx, __shfl_xor(mx, 2));
      mx = fmaxf(mx, __shfl_xor(mx, 4));
      mx = fmaxf(mx, __shfl_xor(mx, 8));
      const float m_new = fmaxf(m_r, mx);
      const float scp = exp2f((m_r - m_new) * LOG2E);
      const float p0 = exp2f((s0 - m_new) * LOG2E);
      const float p1 = exp2f((s1 - m_new) * LOG2E);
      float ts = p0 + p1;
      ts += __shfl_xor(ts, 1);
      ts += __shfl_xor(ts, 2);
      ts += __shfl_xor(ts, 4);
      ts += __shfl_xor(ts, 8);
      l_r = l_r * scp + ts;
      m_r = m_new;
      *(unsigned*)&Pl[ob][srow][c0] = pack2h(p0, p1);
      if ((ln & 15) == 0) sc_l[ob][srow] = scp;
    }

    // ---- rescale + PV(i-2) ----
    if (i >= 2) {
      const int t = i - 2;
      float scc[2][4];
      #pragma unroll
      for (int mt = 0; mt < 2; ++mt)
        #pragma unroll
        for (int r = 0; r < 4; ++r)
          scc[mt][r] = sc_l[sb][mt * 16 + g * 4 + r];
      #pragma unroll
      for (int mt = 0; mt < 2; ++mt)
        #pragma unroll
        for (int dt = 0; dt < 8; ++dt)
          #pragma unroll
          for (int r = 0; r < 4; ++r)
            o[mt][dt][r] *= scc[mt][r];

      half8v pa0 = *(const half8v*)&Pl[sb][li][g * 8];
      half8v pa1 = *(const half8v*)&Pl[sb][16 + li][g * 8];
      __builtin_amdgcn_s_setprio(1);
      #pragma unroll
      for (int dt = 0; dt < 8; ++dt) {
        half8v vb;
        if constexpr (PATH == 0) {
          vb = vreg[dt];
        } else {
          const int d = dbase + dt * 16 + li;
          #pragma unroll
          for (int j = 0; j < 8; ++j) {
            int n = t * 32 + g * 8 + j;
            int nc = (n < LL) ? n : 0;    // clamped rows have P==0
            float f = (nc < PP) ? prefix_v[(size_t)nc * HH + d]
                                : value[((size_t)b * SS + (nc - PP)) * HH + d];
            vb[j] = (_Float16)f;
          }
        }
        o[0][dt] = __builtin_amdgcn_mfma_f32_16x16x32_f16(pa0, vb, o[0][dt], 0, 0, 0);
        o[1][dt] = __builtin_amdgcn_mfma_f32_16x16x32_f16(pa1, vb, o[1][dt], 0, 0, 0);
      }
      __builtin_amdgcn_s_setprio(0);
    }

    // ---- vreg <- V(i-1) (consumed by PV(i-1) at iter i+1) ----
    if constexpr (PATH == 0) {
      if (i >= 1 && i <= NTILES) {
        #pragma unroll
        for (int dt = 0; dt < 8; ++dt)
          vreg[dt] = *(const half8v*)(vbase + (size_t)(dt * 16) * 8);
        vbase += TILE_ELEMS;
      }
    }

    LGKM_BAR();
  }

  // ---- finalize ----
  if ((ln & 15) == 0) l_l[srow] = l_r;
  LGKM_BAR();
  float il[2][4];
  #pragma unroll
  for (int mt = 0; mt < 2; ++mt)
    #pragma unroll
    for (int r = 0; r < 4; ++r)
      il[mt][r] = 1.0f / l_l[mt * 16 + g * 4 + r];
  #pragma unroll
  for (int mt = 0; mt < 2; ++mt)
    #pragma unroll
    for (int dt = 0; dt < 8; ++dt)
      #pragma unroll
      for (int r = 0; r < 4; ++r)
        out[((size_t)(b * SS + q0 + mt * 16 + g * 4 + r)) * HH + dbase + dt * 16 + li]
            = o[mt][dt][r] * il[mt][r];
}

extern "C" void kernel_launch(void* const* d_in, const int* in_sizes, int n_in,
                              void* d_out, int out_size, void* d_ws, size_t ws_size,
                              hipStream_t stream) {
  const float* q        = (const float*)d_in[0];
  const float* key      = (const float*)d_in[1];
  const float* value    = (const float*)d_in[2];
  const float* prefix_k = (const float*)d_in[3];
  const float* prefix_v = (const float*)d_in[4];
  float* out = (float*)d_out;

  const size_t PLANE = (size_t)BB * CHUNKS_PB * 8;              // fp16 elems per plane
  const size_t NEED  = 2 * PLANE * sizeof(unsigned short);      // 67.6 MB

  if (ws_size >= NEED) {
    _Float16* kp = (_Float16*)d_ws;
    _Float16* vp = kp + PLANE;
    conv_k<<<dim3(CHUNKS_PB / 256, BB), 256, 0, stream>>>(prefix_k, key, kp);
    conv_v<<<dim3(CHUNKS_PB / 256, BB), 256, 0, stream>>>(prefix_v, value, vp);
    attn_fused<0><<<512, 512, 0, stream>>>(q, key, value, prefix_k, prefix_v, kp, vp, out);
  } else {
    attn_fused<1><<<512, 512, 0, stream>>>(q, key, value, prefix_k, prefix_v,
                                           nullptr, nullptr, out);
  }
}

// Round 5
// 436.893 us; speedup vs baseline: 6.4657x; 1.0818x over previous
//
#include <hip/hip_runtime.h>
#include <cstdint>
#include <cstddef>

// Problem constants
#define BB 4
#define SS 4096
#define HH 1024
#define PP 10
#define LL 4106              // P + S
#define NTILES 129
#define CHUNKS_PB (NTILES * 4096)   // 16B-chunks per batch plane (= 528384)
#define TILE_ELEMS (4096 * 8)       // fp16 elems per tile in a plane
#define LOG2E 1.44269504088896f
#define DEFER_THR 8.0f

typedef __attribute__((ext_vector_type(8))) _Float16 half8v;  // 4 VGPR MFMA frag
typedef __attribute__((ext_vector_type(4))) float float4v;

union hu16 { _Float16 h; unsigned short u; };

__device__ __forceinline__ half8v cvt8h(float4v f0, float4v f1) {
  half8v h;
  h[0] = (_Float16)f0[0]; h[1] = (_Float16)f0[1];
  h[2] = (_Float16)f0[2]; h[3] = (_Float16)f0[3];
  h[4] = (_Float16)f1[0]; h[5] = (_Float16)f1[1];
  h[6] = (_Float16)f1[2]; h[7] = (_Float16)f1[3];
  return h;
}
__device__ __forceinline__ unsigned pack2h(float a, float b) {
  hu16 x, y; x.h = (_Float16)a; y.h = (_Float16)b;
  return (unsigned)x.u | ((unsigned)y.u << 16);
}

// raw barrier: drain own LDS ops, no vmcnt drain (keeps global loads in flight)
#define LGKM_BAR() do { \
  asm volatile("s_waitcnt lgkmcnt(0)" ::: "memory"); \
  __builtin_amdgcn_s_barrier(); \
  asm volatile("" ::: "memory"); } while (0)

// ---------- pre-kernels: fp16 planes in MFMA-fragment order ----------
__global__ __launch_bounds__(256) void conv_k(const float* __restrict__ prefix_k,
                                              const float* __restrict__ key,
                                              _Float16* __restrict__ kp) {
  const int b = blockIdx.y;
  const int id = blockIdx.x * 256 + threadIdx.x;       // < CHUNKS_PB
  const int li = id & 15, g = (id >> 4) & 3, ktp = (id >> 6) & 31,
            nt = (id >> 11) & 1, it = id >> 12;
  const int n = it * 32 + nt * 16 + li;
  const int d = ktp * 32 + g * 8;
  float4v f0 = {0.f, 0.f, 0.f, 0.f}, f1 = {0.f, 0.f, 0.f, 0.f};
  if (n < LL) {
    const float* src = (n < PP) ? prefix_k + (size_t)n * HH + d
                                : key + ((size_t)b * SS + (n - PP)) * HH + d;
    f0 = *(const float4v*)src; f1 = *(const float4v*)(src + 4);
  }
  *(half8v*)(kp + ((size_t)b * CHUNKS_PB + id) * 8) = cvt8h(f0, f1);
}

__global__ __launch_bounds__(256) void conv_v(const float* __restrict__ prefix_v,
                                              const float* __restrict__ value,
                                              _Float16* __restrict__ vp) {
  const int b = blockIdx.y;
  const int id = blockIdx.x * 256 + threadIdx.x;
  const int d = id & 1023, g = (id >> 10) & 3, it = id >> 12;
  const int nb = it * 32 + g * 8;
  half8v h;
  #pragma unroll
  for (int j = 0; j < 8; ++j) {
    int n = nb + j;
    float f = 0.f;
    if (n < LL)
      f = (n < PP) ? prefix_v[(size_t)n * HH + d]
                   : value[((size_t)b * SS + (n - PP)) * HH + d];
    h[j] = (_Float16)f;
  }
  *(half8v*)(vp + ((size_t)b * CHUNKS_PB + id) * 8) = h;
}

// ---------------- fused flash attention, v5 ----------------
// Same dataflow as v4 (1 barrier/iter, 3-deep pipeline), but the steady-state
// loop is one straight-line basic block (QK(i) + softmax(i-1) + PV(i-2) +
// prefetches) so the scheduler interleaves MFMA/VALU/DS; plus defer-rescale.
template<int PATH>
__global__ __launch_bounds__(512, 2) void attn_fused(
    const float* __restrict__ q,
    const float* __restrict__ key,
    const float* __restrict__ value,
    const float* __restrict__ prefix_k,
    const float* __restrict__ prefix_v,
    const _Float16* __restrict__ kp,
    const _Float16* __restrict__ vp,
    float* __restrict__ out)
{
  __shared__ __align__(16) float sbuf[2][8][32][36];     // 73.7 KB, double-banked
  __shared__ __align__(16) unsigned short Pl[2][32][40]; // 5.1 KB
  __shared__ float sc_l[2][32];
  __shared__ float l_l[32];

  const int tid = threadIdx.x;
  const int w = tid >> 6, ln = tid & 63, g = ln >> 4, li = ln & 15;
  const int bid = blockIdx.x, xcd = bid & 7, b = xcd >> 1;
  const int qt = ((bid >> 3) << 1) | (xcd & 1);
  const int q0 = qt * 32;
  const int dbase = w * 128;

  // Q fragments fp16: A-layout row=li, k=g*8+j
  half8v qf[2][4];
  #pragma unroll
  for (int mt = 0; mt < 2; ++mt)
    #pragma unroll
    for (int kt = 0; kt < 4; ++kt) {
      const float* p = q + ((size_t)(b * SS + q0 + mt * 16 + li)) * HH + dbase + kt * 32 + g * 8;
      qf[mt][kt] = cvt8h(*(const float4v*)p, *(const float4v*)(p + 4));
    }

  float4v z4 = {0.f, 0.f, 0.f, 0.f};
  float4v o[2][8];
  #pragma unroll
  for (int mt = 0; mt < 2; ++mt)
    #pragma unroll
    for (int dt = 0; dt < 8; ++dt) o[mt][dt] = z4;
  float m_r = -1e30f, l_r = 0.f;

  const _Float16* kbase = kp + ((size_t)b * CHUNKS_PB + (size_t)(w * 4) * 64 + g * 16 + li) * 8;
  const _Float16* vbase = vp + ((size_t)b * CHUNKS_PB + (size_t)g * 1024 + dbase + li) * 8;

  half8v kreg[8];   // K(i) during iter i
  half8v vreg[8];   // V(i-2) during iter i
  if constexpr (PATH == 0) {
    #pragma unroll
    for (int kt = 0; kt < 4; ++kt)
      #pragma unroll
      for (int nt = 0; nt < 2; ++nt)
        kreg[kt * 2 + nt] = *(const half8v*)(kbase + (size_t)(nt * 2048 + kt * 64) * 8);
  }

  const int srow = w * 4 + (ln >> 4);     // slab row this lane helps with
  const int c0 = (ln & 15) * 2;

  // ---- phase helpers (inlined; steady loop becomes one basic block) ----
  auto do_qk = [&](int i) __attribute__((always_inline)) {
    float4v sacc[2][2];
    sacc[0][0] = z4; sacc[0][1] = z4; sacc[1][0] = z4; sacc[1][1] = z4;
    #pragma unroll
    for (int kt = 0; kt < 4; ++kt) {
      half8v kb[2];
      if constexpr (PATH == 0) {
        kb[0] = kreg[kt * 2 + 0]; kb[1] = kreg[kt * 2 + 1];
      } else {
        #pragma unroll
        for (int nt = 0; nt < 2; ++nt) {
          int n = i * 32 + nt * 16 + li;
          int nc = (n < LL) ? n : 0;
          const float* kpp = (nc < PP) ? (prefix_k + (size_t)nc * HH)
                                       : (key + ((size_t)b * SS + (nc - PP)) * HH);
          kpp += dbase + kt * 32 + g * 8;
          kb[nt] = cvt8h(*(const float4v*)kpp, *(const float4v*)(kpp + 4));
        }
      }
      #pragma unroll
      for (int mt = 0; mt < 2; ++mt)
        #pragma unroll
        for (int nt = 0; nt < 2; ++nt)
          sacc[mt][nt] = __builtin_amdgcn_mfma_f32_16x16x32_f16(qf[mt][kt], kb[nt], sacc[mt][nt], 0, 0, 0);
    }
    // C/D: row = g*4+r, col = li
    #pragma unroll
    for (int mt = 0; mt < 2; ++mt)
      #pragma unroll
      for (int nt = 0; nt < 2; ++nt)
        #pragma unroll
        for (int r = 0; r < 4; ++r)
          sbuf[i & 1][w][mt * 16 + g * 4 + r][nt * 16 + li] = sacc[mt][nt][r];
    // prefetch kreg <- K(i+1)  (benign 1-tile overrun into vp after last tile)
    if constexpr (PATH == 0) {
      kbase += TILE_ELEMS;
      #pragma unroll
      for (int kt = 0; kt < 4; ++kt)
        #pragma unroll
        for (int nt = 0; nt < 2; ++nt)
          kreg[kt * 2 + nt] = *(const half8v*)(kbase + (size_t)(nt * 2048 + kt * 64) * 8);
    }
  };

  auto do_softmax = [&](int t) __attribute__((always_inline)) {
    const int bk = t & 1;
    float s0 = 0.f, s1 = 0.f;
    #pragma unroll
    for (int bw = 0; bw < 8; ++bw) {
      float2 tv = *(const float2*)&sbuf[bk][bw][srow][c0];
      s0 += tv.x; s1 += tv.y;
    }
    if constexpr (PATH == 1) {
      if (t * 32 + c0 >= LL)     s0 = -1e30f;
      if (t * 32 + c0 + 1 >= LL) s1 = -1e30f;
    }
    float mx = fmaxf(s0, s1);
    mx = fmaxf(mx, __shfl_xor(mx, 1));
    mx = fmaxf(mx, __shfl_xor(mx, 2));
    mx = fmaxf(mx, __shfl_xor(mx, 4));
    mx = fmaxf(mx, __shfl_xor(mx, 8));
    // defer-rescale: keep old max unless some row grew by > THR
    const bool stable = (mx <= m_r + DEFER_THR);
    float m_new, scp;
    if (__ballot(stable) == 0xFFFFFFFFFFFFFFFFull) {   // wave-uniform
      m_new = m_r; scp = 1.0f;
    } else {
      m_new = fmaxf(m_r, mx);
      scp = exp2f((m_r - m_new) * LOG2E);
    }
    const float p0 = exp2f((s0 - m_new) * LOG2E);      // bounded by 2^11.5, fp16-safe
    const float p1 = exp2f((s1 - m_new) * LOG2E);
    float ts = p0 + p1;
    ts += __shfl_xor(ts, 1);
    ts += __shfl_xor(ts, 2);
    ts += __shfl_xor(ts, 4);
    ts += __shfl_xor(ts, 8);
    l_r = l_r * scp + ts;
    m_r = m_new;
    *(unsigned*)&Pl[bk][srow][c0] = pack2h(p0, p1);
    if ((ln & 15) == 0) sc_l[bk][srow] = scp;
  };

  auto do_pv = [&](int t) __attribute__((always_inline)) {
    const int bk = t & 1;
    float scc[2][4];
    bool need = false;
    #pragma unroll
    for (int mt = 0; mt < 2; ++mt)
      #pragma unroll
      for (int r = 0; r < 4; ++r) {
        scc[mt][r] = sc_l[bk][mt * 16 + g * 4 + r];
        need = need || (scc[mt][r] != 1.0f);
      }
    if (__any(need)) {                                  // wave-uniform
      #pragma unroll
      for (int mt = 0; mt < 2; ++mt)
        #pragma unroll
        for (int dt = 0; dt < 8; ++dt)
          #pragma unroll
          for (int r = 0; r < 4; ++r)
            o[mt][dt][r] *= scc[mt][r];
    }
    half8v pa0 = *(const half8v*)&Pl[bk][li][g * 8];
    half8v pa1 = *(const half8v*)&Pl[bk][16 + li][g * 8];
    #pragma unroll
    for (int dt = 0; dt < 8; ++dt) {
      half8v vb;
      if constexpr (PATH == 0) {
        vb = vreg[dt];
      } else {
        const int d = dbase + dt * 16 + li;
        #pragma unroll
        for (int j = 0; j < 8; ++j) {
          int n = t * 32 + g * 8 + j;
          int nc = (n < LL) ? n : 0;    // clamped rows have P==0
          float f = (nc < PP) ? prefix_v[(size_t)nc * HH + d]
                              : value[((size_t)b * SS + (nc - PP)) * HH + d];
          vb[j] = (_Float16)f;
        }
      }
      o[0][dt] = __builtin_amdgcn_mfma_f32_16x16x32_f16(pa0, vb, o[0][dt], 0, 0, 0);
      o[1][dt] = __builtin_amdgcn_mfma_f32_16x16x32_f16(pa1, vb, o[1][dt], 0, 0, 0);
    }
  };

  auto load_v = [&](int) __attribute__((always_inline)) {
    if constexpr (PATH == 0) {
      #pragma unroll
      for (int dt = 0; dt < 8; ++dt)
        vreg[dt] = *(const half8v*)(vbase + (size_t)(dt * 16) * 8);
      vbase += TILE_ELEMS;
    }
  };

  // ---- pipeline: prologue / steady / epilogue ----
  do_qk(0);
  LGKM_BAR();
  do_qk(1); do_softmax(0); load_v(0);
  LGKM_BAR();
  for (int i = 2; i < NTILES; ++i) {
    do_qk(i);
    do_softmax(i - 1);
    do_pv(i - 2);
    load_v(i - 1);
    LGKM_BAR();
  }
  do_softmax(NTILES - 1); do_pv(NTILES - 2); load_v(NTILES - 1);
  LGKM_BAR();
  do_pv(NTILES - 1);

  // ---- finalize ----
  if ((ln & 15) == 0) l_l[srow] = l_r;
  LGKM_BAR();
  float il[2][4];
  #pragma unroll
  for (int mt = 0; mt < 2; ++mt)
    #pragma unroll
    for (int r = 0; r < 4; ++r)
      il[mt][r] = 1.0f / l_l[mt * 16 + g * 4 + r];
  #pragma unroll
  for (int mt = 0; mt < 2; ++mt)
    #pragma unroll
    for (int dt = 0; dt < 8; ++dt)
      #pragma unroll
      for (int r = 0; r < 4; ++r)
        out[((size_t)(b * SS + q0 + mt * 16 + g * 4 + r)) * HH + dbase + dt * 16 + li]
            = o[mt][dt][r] * il[mt][r];
}

extern "C" void kernel_launch(void* const* d_in, const int* in_sizes, int n_in,
                              void* d_out, int out_size, void* d_ws, size_t ws_size,
                              hipStream_t stream) {
  const float* q        = (const float*)d_in[0];
  const float* key      = (const float*)d_in[1];
  const float* value    = (const float*)d_in[2];
  const float* prefix_k = (const float*)d_in[3];
  const float* prefix_v = (const float*)d_in[4];
  float* out = (float*)d_out;

  const size_t PLANE = (size_t)BB * CHUNKS_PB * 8;              // fp16 elems per plane
  const size_t NEED  = 2 * PLANE * sizeof(unsigned short);      // 67.6 MB

  if (ws_size >= NEED) {
    _Float16* kp = (_Float16*)d_ws;
    _Float16* vp = kp + PLANE;
    conv_k<<<dim3(CHUNKS_PB / 256, BB), 256, 0, stream>>>(prefix_k, key, kp);
    conv_v<<<dim3(CHUNKS_PB / 256, BB), 256, 0, stream>>>(prefix_v, value, vp);
    attn_fused<0><<<512, 512, 0, stream>>>(q, key, value, prefix_k, prefix_v, kp, vp, out);
  } else {
    attn_fused<1><<<512, 512, 0, stream>>>(q, key, value, prefix_k, prefix_v,
                                           nullptr, nullptr, out);
  }
}